// Round 13
// baseline (244.026 us; speedup 1.0000x reference)
//
#include <hip/hip_runtime.h>

// ---------------------------------------------------------------------------
// TripletContrastiveLoss on MI355X (gfx950)  — Round 13
// Base: R12 (180 µs; tile 93 µs). Two independently-measurable changes:
// 1) tile: m97-faithful K-loop — BK=64, SINGLE-buffered 32 KB LDS, 2 barriers
//    per step, global_load_lds width=16 staging (8 async instr/wave/step,
//    32 MFMAs/wave/step, 16 steps). m97's histogram shows 2 async loads per
//    thread per 16-MFMA iter = BK=64; R11 proved BK=64 via VGPR staging
//    spills (WRITE 7->296 MB) — async staging holds zero registers.
// 2) launcher: 7 -> 5 nodes (drop cnt memset — scan writes cnt[0]
//    unconditionally; fuse reduce+finalize into single-block reduce_one).
//    The posmin/negmin 0xFF memset STAYS in the launcher.
// ---------------------------------------------------------------------------

#define B_ROWS 8192
#define DIM    1024

typedef __bf16 bf16x8 __attribute__((ext_vector_type(8)));
typedef float  f32x4  __attribute__((ext_vector_type(4)));

__device__ __forceinline__ unsigned short f2bf_rne(float x) {
    unsigned u = __float_as_uint(x);
    unsigned r = (u + 0x7FFFu + ((u >> 16) & 1u)) >> 16;
    return (unsigned short)r;
}
__device__ __forceinline__ float bf2f(unsigned short h) {
    return __uint_as_float(((unsigned)h) << 16);
}

// Async global->LDS, 16 B per lane. LDS dest must be wave-uniform; HW places
// lane i at base + 16*i.
__device__ __forceinline__ void async_copy16(const void* g, void* l) {
    __builtin_amdgcn_global_load_lds(
        (const __attribute__((address_space(1))) unsigned int*)g,
        (__attribute__((address_space(3))) unsigned int*)l,
        16, 0, 0);
}

// ---------------------------------------------------------------------------
// Kernel 0: slot assignment via LDS prefix scan. 1 block x 256 threads,
// 32 rows/thread. Zero atomics. slotOf overlays the posmin region (consumed
// by normalize_rows, then clobbered by the 0xFF memset — stream-ordered).
// Writes cnt[0] = nA unconditionally (replaces the cnt memset).
// ---------------------------------------------------------------------------
__global__ __launch_bounds__(256) void compute_slots(
    const int* __restrict__ dom, int* __restrict__ slotOf,
    unsigned* __restrict__ cnt)
{
    __shared__ int cnts[256];
    __shared__ int base[257];
    const int t = threadIdx.x;
    const int p0 = t * 32;

    unsigned mask = 0u; int c = 0;
    #pragma unroll
    for (int i = 0; i < 32; ++i) {
        const int isA = (dom[p0 + i] == 0) ? 1 : 0;
        mask |= ((unsigned)isA) << i;
        c += isA;
    }
    cnts[t] = c;
    __syncthreads();
    if (t == 0) {
        int acc = 0;
        for (int i = 0; i < 256; ++i) { base[i] = acc; acc += cnts[i]; }
        base[256] = acc;
        cnt[0] = (unsigned)acc;                  // nA
    }
    __syncthreads();
    const int nA = base[256];
    int aB = base[t];
    #pragma unroll
    for (int i = 0; i < 32; ++i) {
        const int isA = (mask >> i) & 1;
        slotOf[p0 + i] = isA ? aB : nA + (p0 + i - aB);
        aB += isA;
    }
}

// ---------------------------------------------------------------------------
// Kernel 1: one row per WAVE. 2048 blocks x 256 threads (4 waves). Wave-local
// shuffle reductions only. L2-normalize fp32, round to bf16, scatter to slot.
// sqG[slot] = sum of squares of the bf16-ROUNDED row.
// ---------------------------------------------------------------------------
__global__ __launch_bounds__(256) void normalize_rows(
    const float* __restrict__ feat, const int* __restrict__ labels,
    const int* __restrict__ slotOf, unsigned short* __restrict__ G,
    int* __restrict__ labG, float* __restrict__ sqG)
{
    const int wv = threadIdx.x >> 6, lane = threadIdx.x & 63;
    const int row = blockIdx.x * 4 + wv;

    const float4* src = (const float4*)(feat + (size_t)row * DIM);
    float4 v[4];
    float ss = 0.0f;
    #pragma unroll
    for (int j = 0; j < 4; ++j) {
        v[j] = src[j * 64 + lane];
        ss += v[j].x * v[j].x + v[j].y * v[j].y + v[j].z * v[j].z + v[j].w * v[j].w;
    }
    #pragma unroll
    for (int s = 32; s > 0; s >>= 1) ss += __shfl_xor(ss, s);
    const float inv = 1.0f / fmaxf(sqrtf(ss), 1e-12f);

    const int slot = slotOf[row];
    unsigned short ub[16];
    float ss2 = 0.0f;
    #pragma unroll
    for (int j = 0; j < 4; ++j) {
        const float f0 = v[j].x * inv, f1 = v[j].y * inv,
                    f2 = v[j].z * inv, f3 = v[j].w * inv;
        ub[j * 4 + 0] = f2bf_rne(f0); ub[j * 4 + 1] = f2bf_rne(f1);
        ub[j * 4 + 2] = f2bf_rne(f2); ub[j * 4 + 3] = f2bf_rne(f3);
        #pragma unroll
        for (int q = 0; q < 4; ++q) {
            const float fr = bf2f(ub[j * 4 + q]);
            ss2 += fr * fr;
        }
    }
    #pragma unroll
    for (int s = 32; s > 0; s >>= 1) ss2 += __shfl_xor(ss2, s);
    if (lane == 0) {
        sqG[slot]  = ss2;
        labG[slot] = labels[row];
    }
    ushort4* dst = (ushort4*)(G + (size_t)slot * DIM);
    #pragma unroll
    for (int j = 0; j < 4; ++j) {
        ushort4 pk;
        pk.x = ub[j * 4 + 0]; pk.y = ub[j * 4 + 1];
        pk.z = ub[j * 4 + 2]; pk.w = ub[j * 4 + 3];
        dst[j * 64 + lane] = pk;
    }
}

// ---------------------------------------------------------------------------
// Kernel 2: persistent 128x128 tiles, 4 waves (each 64x64 via 4x4 of
// 16x16x32 bf16 MFMA). K=1024 in 16 steps of BK=64 (128 B/row/step).
// m97 structure: SINGLE-buffered LDS (A,F: 16 KB each, unpadded 128-B rows),
// staging via global_load_lds width=16 (chunk = 8 rows x 128 B = 1 KB =
// one wave-instr; 4 chunks/wave/array), TWO barriers per step:
//   sync#1 drains vmcnt -> buffer holds step k; MFMAs; sync#2 -> safe to
//   overwrite; issue async for k+1.
// Epilogue: min d^2 per anchor row -> atomicMin (uint order, d^2 >= 0).
// ---------------------------------------------------------------------------
__global__ __launch_bounds__(256) void tile_mindist(
    const unsigned short* __restrict__ G, const int* __restrict__ labG,
    const float* __restrict__ sqG, const unsigned* __restrict__ cnt,
    unsigned* __restrict__ posmin, unsigned* __restrict__ negmin)
{
    const int nA = (int)cnt[0];
    const int nF = B_ROWS - nA;
    const int nTA = (nA + 127) >> 7;
    const int nTF = (nF + 127) >> 7;
    const int total = nTA * nTF;

    __shared__ __align__(16) unsigned short As[128 * 64];  // 16 KB
    __shared__ __align__(16) unsigned short Fs[128 * 64];  // 16 KB

    const int t = threadIdx.x;
    const int lane = t & 63, w = t >> 6;
    const int wm = w >> 1, wn = w & 1;          // wave sub-tile coords (x64)
    const int l15 = lane & 15, quad = lane >> 4;

    // Async staging: chunk c = rows [8c, 8c+8) x 128 B; wave w owns chunks
    // 4w..4w+3 of both arrays. Lane: row 8c + (lane>>3), byte col (lane&7)*16.
    const int c0 = 4 * w;
    const int crow = lane >> 3;
    const int cbyte = (lane & 7) * 16;

    // Fragment read offsets (shorts), row stride 64 shorts (128 B).
    const int rdA = (wm * 64 + l15) * 64 + quad * 8;
    const int rdF = (wn * 64 + l15) * 64 + quad * 8;

    const char* Gb = (const char*)G;

    for (int tile = blockIdx.x; tile < total; tile += gridDim.x) {
        const int tx = tile % nTA;
        const int ty = tile / nTA;
        const int rowA0 = tx * 128;
        const int rowF0 = nA + ty * 128;

        const char* ga[4]; const char* gf[4];
        #pragma unroll
        for (int h = 0; h < 4; ++h) {
            const int c = c0 + h;
            const int rA = rowA0 + 8 * c + crow;            // < 8192 always
            int rF = rowF0 + 8 * c + crow;
            if (rF > B_ROWS - 1) rF = B_ROWS - 1;           // clamp; masked later
            ga[h] = Gb + (size_t)rA * (DIM * 2) + cbyte;
            gf[h] = Gb + (size_t)rF * (DIM * 2) + cbyte;
        }

        f32x4 acc[4][4] = {};

        // Prologue: issue async for step 0.
        #pragma unroll
        for (int h = 0; h < 4; ++h) {
            async_copy16(ga[h], &As[(c0 + h) * 512]);
            async_copy16(gf[h], &Fs[(c0 + h) * 512]);
        }

        for (int step = 0; step < 16; ++step) {
            __syncthreads();                     // drain vmcnt: step data ready

            bf16x8 a[4][2], b[4][2];
            #pragma unroll
            for (int u = 0; u < 2; ++u) {
                #pragma unroll
                for (int fm = 0; fm < 4; ++fm)
                    a[fm][u] = *(const bf16x8*)(&As[rdA + fm * 1024 + u * 32]);
                #pragma unroll
                for (int fn = 0; fn < 4; ++fn)
                    b[fn][u] = *(const bf16x8*)(&Fs[rdF + fn * 1024 + u * 32]);
            }
            #pragma unroll
            for (int u = 0; u < 2; ++u)
                #pragma unroll
                for (int fm = 0; fm < 4; ++fm)
                    #pragma unroll
                    for (int fn = 0; fn < 4; ++fn)
                        acc[fm][fn] = __builtin_amdgcn_mfma_f32_16x16x32_bf16(
                            a[fm][u], b[fn][u], acc[fm][fn], 0, 0, 0);

            __syncthreads();                     // reads done: safe to overwrite
            if (step < 15) {
                const int off = (step + 1) * 128;
                #pragma unroll
                for (int h = 0; h < 4; ++h) {
                    async_copy16(ga[h] + off, &As[(c0 + h) * 512]);
                    async_copy16(gf[h] + off, &Fs[(c0 + h) * 512]);
                }
            }
        }

        // Epilogue. C/D layout: col = lane&15 (field), row = quad*4+reg (anchor).
        const float INFV = __uint_as_float(0x7f800000u);
        float sqf[4]; int lf_[4]; bool vf[4];
        #pragma unroll
        for (int fn = 0; fn < 4; ++fn) {
            const int rf = rowF0 + wn * 64 + fn * 16 + l15;
            vf[fn] = rf < B_ROWS;
            const int rc = vf[fn] ? rf : (B_ROWS - 1);
            sqf[fn] = sqG[rc];
            lf_[fn] = labG[rc];
        }
        #pragma unroll
        for (int fm = 0; fm < 4; ++fm) {
            #pragma unroll
            for (int r = 0; r < 4; ++r) {
                const int ra = rowA0 + wm * 64 + fm * 16 + quad * 4 + r;
                const bool va = ra < nA;
                const int rac = va ? ra : 0;
                const float sqa = sqG[rac];
                const int la_ = labG[rac];
                float pmin = INFV, nmin = INFV;
                #pragma unroll
                for (int fn = 0; fn < 4; ++fn) {
                    const float dd = fmaxf(sqa + sqf[fn] - 2.0f * acc[fm][fn][r], 0.0f);
                    if (vf[fn]) {
                        if (la_ == lf_[fn]) pmin = fminf(pmin, dd);
                        else                nmin = fminf(nmin, dd);
                    }
                }
                #pragma unroll
                for (int s = 1; s < 16; s <<= 1) {
                    pmin = fminf(pmin, __shfl_xor(pmin, s));
                    nmin = fminf(nmin, __shfl_xor(nmin, s));
                }
                if (l15 == 0 && va) {
                    if (pmin < INFV) atomicMin(&posmin[ra], __float_as_uint(pmin));
                    if (nmin < INFV) atomicMin(&negmin[ra], __float_as_uint(nmin));
                }
            }
        }
        __syncthreads();   // protect LDS before next tile's prologue writes
    }
}

// ---------------------------------------------------------------------------
// Kernel 3: fused final reduce. 1 block x 256 threads, 32 independent load
// pairs per thread, wave+LDS reduce, write out[0]. Untouched slots stay
// 0xFFFFFFFF and drop out as invalid.
// ---------------------------------------------------------------------------
__global__ __launch_bounds__(256) void reduce_one(
    const unsigned* __restrict__ posmin, const unsigned* __restrict__ negmin,
    float* __restrict__ out)
{
    const int t = threadIdx.x;
    const int lane = t & 63, w = t >> 6;
    float tl = 0.0f, c = 0.0f;
    #pragma unroll
    for (int j = 0; j < 32; ++j) {
        const int i = j * 256 + t;
        const unsigned up = posmin[i], un = negmin[i];
        if (up != 0xFFFFFFFFu && un != 0xFFFFFFFFu) {
            const float pd = sqrtf(__uint_as_float(up));
            const float nd = sqrtf(__uint_as_float(un));
            tl += fmaxf(pd - nd + 0.3f, 0.0f);
            c += 1.0f;
        }
    }
    #pragma unroll
    for (int s = 32; s > 0; s >>= 1) {
        tl += __shfl_down(tl, s);
        c  += __shfl_down(c, s);
    }
    __shared__ float sb[8];
    if (lane == 0) { sb[w] = tl; sb[4 + w] = c; }
    __syncthreads();
    if (t == 0) {
        const float s = sb[0] + sb[1] + sb[2] + sb[3];
        const float cc = sb[4] + sb[5] + sb[6] + sb[7];
        out[0] = (cc > 0.0f) ? s / fmaxf(cc, 1.0f) : 0.0f;
    }
}

// ---------------------------------------------------------------------------
extern "C" void kernel_launch(void* const* d_in, const int* in_sizes, int n_in,
                              void* d_out, int out_size, void* d_ws, size_t ws_size,
                              hipStream_t stream) {
    const float* feat  = (const float*)d_in[0];
    const int* labels  = (const int*)d_in[1];
    const int* dom     = (const int*)d_in[2];
    float* out = (float*)d_out;

    char* ws = (char*)d_ws;
    // Workspace layout (bytes) — identical footprint to validated R4/R8 layout:
    unsigned short* G   = (unsigned short*)(ws);                 // 16,777,216
    int*      labG      = (int*)(ws + 16777216);                 //     32,768
    float*    sqG       = (float*)(ws + 16809984);               //     32,768
    unsigned* posmin    = (unsigned*)(ws + 16842752);            //     32,768
    unsigned* negmin    = (unsigned*)(ws + 16875520);            //     32,768
    unsigned* cnt       = (unsigned*)(ws + 16908288);            //  8 (nA)
    // slotOf OVERLAYS posmin: written by compute_slots, consumed by
    // normalize_rows, then clobbered by the 0xFF memset (stream-ordered).
    int*      slotOf    = (int*)(ws + 16842752);

    compute_slots<<<1, 256, 0, stream>>>(dom, slotOf, cnt);
    normalize_rows<<<B_ROWS / 4, 256, 0, stream>>>(feat, labels, slotOf,
                                                   G, labG, sqG);

    hipMemsetAsync(posmin, 0xFF, 65536, stream);    // posmin+negmin = +inf bits

    // Max tiles over all nA splits: ceil(a/128)*ceil((8192-a)/128) <= 1056.
    tile_mindist<<<1056, 256, 0, stream>>>(G, labG, sqG, cnt, posmin, negmin);

    reduce_one<<<1, 256, 0, stream>>>(posmin, negmin, out);
}